// Round 1
// baseline (890.166 us; speedup 1.0000x reference)
//
#include <hip/hip_runtime.h>
#include <hip/hip_bf16.h>

// Problem constants (match reference)
#define WSZ 262144   // window size (rows)
#define LL  512      // local feature length (K)
#define GG  128      // global feature length (N)
#define BM  128      // rows per block tile
#define BK  32       // K-chunk (one MFMA K)
#define NCHUNK (WSZ / BM)   // 2048

typedef float f32x4 __attribute__((ext_vector_type(4)));
typedef float f32x4v __attribute__((ext_vector_type(4)));
typedef __bf16 bf16x8 __attribute__((ext_vector_type(8)));

// ---------------------------------------------------------------------------
// K0: convert W1 (fp32 [512,128] row-major) to bf16 in MFMA-B fragment order:
//   dst[((kc*128 + col)*4 + q)*8 + j] = W1[k][col],  k = kc*32 + q*8 + j
// so a lane (col = lane&15, q = lane>>4) does one contiguous 16B load per frag.
// ---------------------------------------------------------------------------
__global__ __launch_bounds__(256) void prep_kernel(const float* __restrict__ W1,
                                                   __bf16* __restrict__ Bfrag) {
    int t = blockIdx.x * 256 + threadIdx.x;   // 0 .. 65535
    int k = t >> 7;
    int col = t & 127;
    float v = W1[t];
    int dst = ((k >> 5) << 12) + (col << 5) + (((k >> 3) & 3) << 3) + (k & 7);
    Bfrag[dst] = (__bf16)v;
}

// ---------------------------------------------------------------------------
// K1: GEMM. Block = 256 threads (4 waves, 2x2 wave grid), tile 128 rows x 128
// cols (full N). K-loop over 16 chunks of 32. A staged fp32->bf16 into LDS
// with row pitch 40 bf16 (80B) so frag ds_read_b128 is ~conflict-free.
// Writes proj+bias to out, and per-column block max to blockMax.
// ---------------------------------------------------------------------------
__global__ __launch_bounds__(256) void gemm_kernel(
        const float* __restrict__ A,       // [WSZ, 512]
        const float* __restrict__ b1,      // [128]
        const __bf16* __restrict__ Bfrag,  // frag-ordered W1 bf16
        float* __restrict__ out,           // [WSZ, 128]
        float* __restrict__ blockMax)      // [NCHUNK, 128]
{
    __shared__ __align__(16) __bf16 ldsA[BM * 40];
    __shared__ float smax[2][GG];

    const int tid  = threadIdx.x;
    const int wave = tid >> 6;
    const int lane = tid & 63;
    const int wr = wave >> 1;       // wave row (0/1): rows wr*64..+64
    const int wc = wave & 1;        // wave col (0/1): cols wc*64..+64
    const int l15 = lane & 15;
    const int q   = lane >> 4;
    const size_t row0 = (size_t)blockIdx.x * BM;

    f32x4 acc[4][4] = {};

    for (int kc = 0; kc < LL / BK; ++kc) {
        __syncthreads();   // protect LDS from previous iter's readers
        // ---- stage A chunk: 128 rows x 32 k, 512 tasks of 8 floats ----
        #pragma unroll
        for (int t = 0; t < 2; ++t) {
            int id  = tid + t * 256;
            int row = id >> 2;
            int kg  = id & 3;
            const float* src = A + (row0 + row) * LL + kc * BK + kg * 8;
            f32x4v v0 = *(const f32x4v*)src;
            f32x4v v1 = *(const f32x4v*)(src + 4);
            bf16x8 b;
            b[0] = (__bf16)v0[0]; b[1] = (__bf16)v0[1];
            b[2] = (__bf16)v0[2]; b[3] = (__bf16)v0[3];
            b[4] = (__bf16)v1[0]; b[5] = (__bf16)v1[1];
            b[6] = (__bf16)v1[2]; b[7] = (__bf16)v1[3];
            *(bf16x8*)&ldsA[row * 40 + kg * 8] = b;
        }
        __syncthreads();

        // ---- B fragments straight from global (L2-resident, 16B/lane) ----
        bf16x8 bfr[4];
        #pragma unroll
        for (int ct = 0; ct < 4; ++ct) {
            int col = wc * 64 + ct * 16 + l15;
            bfr[ct] = *(const bf16x8*)(Bfrag + ((size_t)kc * 128 + col) * 32 + q * 8);
        }
        // ---- A fragments from LDS ----
        bf16x8 afr[4];
        #pragma unroll
        for (int rt = 0; rt < 4; ++rt) {
            int row = wr * 64 + rt * 16 + l15;
            afr[rt] = *(const bf16x8*)&ldsA[row * 40 + q * 8];
        }
        // ---- 16 MFMAs ----
        #pragma unroll
        for (int rt = 0; rt < 4; ++rt)
            #pragma unroll
            for (int ct = 0; ct < 4; ++ct)
                acc[rt][ct] = __builtin_amdgcn_mfma_f32_16x16x32_bf16(
                    afr[rt], bfr[ct], acc[rt][ct], 0, 0, 0);
    }

    // ---- epilogue: bias add, store proj, per-column block max ----
    // D layout: row = q*4 + reg, col = lane&15 (per 16x16 tile)
    float cmax[4];
    #pragma unroll
    for (int ct = 0; ct < 4; ++ct) {
        int col = wc * 64 + ct * 16 + l15;
        float bias = b1[col];
        float m = -__builtin_inff();
        #pragma unroll
        for (int rt = 0; rt < 4; ++rt) {
            #pragma unroll
            for (int r = 0; r < 4; ++r) {
                float v = acc[rt][ct][r] + bias;
                size_t row = row0 + wr * 64 + rt * 16 + q * 4 + r;
                out[row * GG + col] = v;
                m = fmaxf(m, v);
            }
        }
        cmax[ct] = m;
    }
    // reduce the 4 quads (same l15, q = 0..3) -> column max over wave's 64 rows
    #pragma unroll
    for (int ct = 0; ct < 4; ++ct) {
        cmax[ct] = fmaxf(cmax[ct], __shfl_xor(cmax[ct], 16));
        cmax[ct] = fmaxf(cmax[ct], __shfl_xor(cmax[ct], 32));
    }
    if (q == 0) {
        #pragma unroll
        for (int ct = 0; ct < 4; ++ct)
            smax[wr][wc * 64 + ct * 16 + l15] = cmax[ct];
    }
    __syncthreads();
    if (tid < GG)
        blockMax[(size_t)blockIdx.x * GG + tid] = fmaxf(smax[0][tid], smax[1][tid]);
}

// ---------------------------------------------------------------------------
// K2: sequential scan over chunk maxes -> g-seeded EXCLUSIVE prefix max,
// stored in-place. Also writes global_feature_new = max(all, g).
// ---------------------------------------------------------------------------
__global__ __launch_bounds__(128) void scan_kernel(float* __restrict__ blockMax,
                                                   const float* __restrict__ gfeat,
                                                   float* __restrict__ out_gnew) {
    int col = threadIdx.x;
    float run = gfeat[col];
    #pragma unroll 8
    for (int c = 0; c < NCHUNK; ++c) {
        float v = blockMax[(size_t)c * GG + col];
        blockMax[(size_t)c * GG + col] = run;
        run = fmaxf(run, v);
    }
    out_gnew[col] = run;
}

// ---------------------------------------------------------------------------
// K3: per-chunk in-place running max seeded by the exclusive prefix.
// 256 threads = 2 chunks per block.
// ---------------------------------------------------------------------------
__global__ __launch_bounds__(256) void finalize_kernel(float* __restrict__ out,
                                                       const float* __restrict__ exPrefix) {
    int c   = blockIdx.x * 2 + (threadIdx.x >> 7);
    int col = threadIdx.x & 127;
    float run = exPrefix[(size_t)c * GG + col];
    float* p = out + (size_t)c * BM * GG + col;
    #pragma unroll 8
    for (int r = 0; r < BM; ++r) {
        float v = p[(size_t)r * GG];
        run = fmaxf(run, v);
        p[(size_t)r * GG] = run;
    }
}

// ---------------------------------------------------------------------------
extern "C" void kernel_launch(void* const* d_in, const int* in_sizes, int n_in,
                              void* d_out, int out_size, void* d_ws, size_t ws_size,
                              hipStream_t stream) {
    const float* local = (const float*)d_in[0];   // [262144, 512]
    const float* gfeat = (const float*)d_in[1];   // [1, 128]
    const float* W1    = (const float*)d_in[2];   // [512, 128]
    const float* b1    = (const float*)d_in[3];   // [128]
    float* out = (float*)d_out;                   // [262144*128] ++ [128]

    // workspace layout: [0,128KB) bf16 W1 frags; then [NCHUNK,128] fp32 maxes
    __bf16* Bfrag   = (__bf16*)d_ws;                              // 64K elems
    float* blockMax = (float*)((char*)d_ws + (size_t)LL * GG * 2); // 1 MB

    prep_kernel<<<256, 256, 0, stream>>>(W1, Bfrag);
    gemm_kernel<<<NCHUNK, 256, 0, stream>>>(local, b1, Bfrag, out, blockMax);
    scan_kernel<<<1, 128, 0, stream>>>(blockMax, gfeat, out + (size_t)WSZ * GG);
    finalize_kernel<<<NCHUNK / 2, 256, 0, stream>>>(out, blockMax);
}

// Round 2
// 811.940 us; speedup vs baseline: 1.0963x; 1.0963x over previous
//
#include <hip/hip_runtime.h>
#include <hip/hip_bf16.h>

// Problem constants (match reference)
#define WSZ 262144   // window size (rows)
#define LL  512      // local feature length (K)
#define GG  128      // global feature length (N)
#define BM  128      // rows per block tile
#define BK  32       // K-chunk (one MFMA K)
#define NCHUNK (WSZ / BM)   // 2048
#define NEG_INF (-__builtin_inff())

typedef float f32x4 __attribute__((ext_vector_type(4)));
typedef __bf16 bf16x8 __attribute__((ext_vector_type(8)));

// ---------------------------------------------------------------------------
// K0: convert W1 (fp32 [512,128] row-major) to bf16 in MFMA-B fragment order:
//   dst[((kc*128 + col)*4 + q)*8 + j] = W1[k][col],  k = kc*32 + q*8 + j
// ---------------------------------------------------------------------------
__global__ __launch_bounds__(256) void prep_kernel(const float* __restrict__ W1,
                                                   __bf16* __restrict__ Bfrag) {
    int t = blockIdx.x * 256 + threadIdx.x;   // 0 .. 65535
    int k = t >> 7;
    int col = t & 127;
    float v = W1[t];
    int dst = ((k >> 5) << 12) + (col << 5) + (((k >> 3) & 3) << 3) + (k & 7);
    Bfrag[dst] = (__bf16)v;
}

// ---------------------------------------------------------------------------
// K1: GEMM. 256 threads (4 waves, 2x2 wave grid), tile 128x128 (full N).
// Software-pipelined: global loads for chunk k+1 issue before MFMAs of k.
// A staged fp32->bf16 into LDS, pitch 40 bf16. Nontemporal A loads (stream-
// once) and proj stores (128MB > L2). Writes per-column block max to blockMax.
// ---------------------------------------------------------------------------
__global__ __launch_bounds__(256) void gemm_kernel(
        const float* __restrict__ A,       // [WSZ, 512]
        const float* __restrict__ b1,      // [128]
        const __bf16* __restrict__ Bfrag,  // frag-ordered W1 bf16
        float* __restrict__ out,           // [WSZ, 128]
        float* __restrict__ blockMax)      // [NCHUNK, 128]
{
    __shared__ __align__(16) __bf16 ldsA[BM * 40];
    __shared__ float smax[2][GG];

    const int tid  = threadIdx.x;
    const int wave = tid >> 6;
    const int lane = tid & 63;
    const int wr = wave >> 1;
    const int wc = wave & 1;
    const int l15 = lane & 15;
    const int q   = lane >> 4;
    const size_t row0 = (size_t)blockIdx.x * BM;

    // staging task geometry: 512 tasks of 8 floats; this thread owns 2 tasks
    const int rowA0 = tid >> 2,        kgA0 = tid & 3;
    const int rowA1 = (tid + 256) >> 2, kgA1 = tid & 3;   // +256 keeps kg, row+64
    const float* sA0 = A + (row0 + rowA0) * LL + kgA0 * 8;
    const float* sA1 = A + (row0 + rowA1) * LL + kgA1 * 8;

    f32x4 acc[4][4] = {};

    // preload chunk 0
    f32x4 c00 = __builtin_nontemporal_load((const f32x4*)sA0);
    f32x4 c01 = __builtin_nontemporal_load((const f32x4*)(sA0 + 4));
    f32x4 c10 = __builtin_nontemporal_load((const f32x4*)sA1);
    f32x4 c11 = __builtin_nontemporal_load((const f32x4*)(sA1 + 4));

    for (int kc = 0; kc < LL / BK; ++kc) {
        // pack current chunk to bf16 (register-only)
        bf16x8 b0, b1;
        b0[0] = (__bf16)c00[0]; b0[1] = (__bf16)c00[1];
        b0[2] = (__bf16)c00[2]; b0[3] = (__bf16)c00[3];
        b0[4] = (__bf16)c01[0]; b0[5] = (__bf16)c01[1];
        b0[6] = (__bf16)c01[2]; b0[7] = (__bf16)c01[3];
        b1[0] = (__bf16)c10[0]; b1[1] = (__bf16)c10[1];
        b1[2] = (__bf16)c10[2]; b1[3] = (__bf16)c10[3];
        b1[4] = (__bf16)c11[0]; b1[5] = (__bf16)c11[1];
        b1[6] = (__bf16)c11[2]; b1[7] = (__bf16)c11[3];

        __syncthreads();   // previous iter's LDS readers done
        *(bf16x8*)&ldsA[rowA0 * 40 + kgA0 * 8] = b0;
        *(bf16x8*)&ldsA[rowA1 * 40 + kgA1 * 8] = b1;

        // prefetch next chunk (clamped; redundant reload on last iter is free)
        const int kn = (kc < LL / BK - 1) ? kc + 1 : kc;
        c00 = __builtin_nontemporal_load((const f32x4*)(sA0 + kn * BK));
        c01 = __builtin_nontemporal_load((const f32x4*)(sA0 + kn * BK + 4));
        c10 = __builtin_nontemporal_load((const f32x4*)(sA1 + kn * BK));
        c11 = __builtin_nontemporal_load((const f32x4*)(sA1 + kn * BK + 4));

        __syncthreads();   // LDS tile ready

        // B fragments from global (128KB, L2-resident)
        bf16x8 bfr[4];
        #pragma unroll
        for (int ct = 0; ct < 4; ++ct) {
            int col = wc * 64 + ct * 16 + l15;
            bfr[ct] = *(const bf16x8*)(Bfrag + ((size_t)kc * 128 + col) * 32 + q * 8);
        }
        // A fragments from LDS
        bf16x8 afr[4];
        #pragma unroll
        for (int rt = 0; rt < 4; ++rt) {
            int row = wr * 64 + rt * 16 + l15;
            afr[rt] = *(const bf16x8*)&ldsA[row * 40 + q * 8];
        }
        #pragma unroll
        for (int rt = 0; rt < 4; ++rt)
            #pragma unroll
            for (int ct = 0; ct < 4; ++ct)
                acc[rt][ct] = __builtin_amdgcn_mfma_f32_16x16x32_bf16(
                    afr[rt], bfr[ct], acc[rt][ct], 0, 0, 0);
    }

    // ---- epilogue: bias add, store proj (NT), per-column block max ----
    float cmax[4];
    #pragma unroll
    for (int ct = 0; ct < 4; ++ct) {
        int col = wc * 64 + ct * 16 + l15;
        float bias = b1[col];
        float m = NEG_INF;
        #pragma unroll
        for (int rt = 0; rt < 4; ++rt) {
            #pragma unroll
            for (int r = 0; r < 4; ++r) {
                float v = acc[rt][ct][r] + bias;
                size_t row = row0 + wr * 64 + rt * 16 + q * 4 + r;
                __builtin_nontemporal_store(v, &out[row * GG + col]);
                m = fmaxf(m, v);
            }
        }
        cmax[ct] = m;
    }
    #pragma unroll
    for (int ct = 0; ct < 4; ++ct) {
        cmax[ct] = fmaxf(cmax[ct], __shfl_xor(cmax[ct], 16));
        cmax[ct] = fmaxf(cmax[ct], __shfl_xor(cmax[ct], 32));
    }
    if (q == 0) {
        #pragma unroll
        for (int ct = 0; ct < 4; ++ct)
            smax[wr][wc * 64 + ct * 16 + l15] = cmax[ct];
    }
    __syncthreads();
    if (tid < GG)
        blockMax[(size_t)blockIdx.x * GG + tid] = fmaxf(smax[0][tid], smax[1][tid]);
}

// ---------------------------------------------------------------------------
// K2: parallel scan over chunk maxes. One 1024-thread block: 8 segments x
// 128 cols. Phase A: segment reduce (staged 8-load groups). Phase B: tiny
// LDS exclusive combine seeded with g. Phase C: segment-local exclusive
// prefix writeback (loads explicitly staged before stores -> pipelined).
// Also writes global_feature_new.
// ---------------------------------------------------------------------------
__global__ __launch_bounds__(1024) void scan_kernel(float* __restrict__ blockMax,
                                                    const float* __restrict__ gfeat,
                                                    float* __restrict__ out_gnew) {
    __shared__ float segTot[8][GG];
    const int col = threadIdx.x & 127;
    const int seg = threadIdx.x >> 7;           // 0..7
    const int CPS = NCHUNK / 8;                 // 256 chunks per segment
    float* base = blockMax + (size_t)seg * CPS * GG + col;

    float m = NEG_INF;
    for (int g = 0; g < CPS / 8; ++g) {
        float v[8];
        #pragma unroll
        for (int j = 0; j < 8; ++j) v[j] = base[(size_t)(g * 8 + j) * GG];
        #pragma unroll
        for (int j = 0; j < 8; ++j) m = fmaxf(m, v[j]);
    }
    segTot[seg][col] = m;
    __syncthreads();

    float run = gfeat[col];
    #pragma unroll
    for (int s = 0; s < 7; ++s) {
        float t = segTot[s][col];
        if (s < seg) run = fmaxf(run, t);
    }
    if (seg == 7)
        out_gnew[col] = fmaxf(run, segTot[7][col]);

    for (int g = 0; g < CPS / 8; ++g) {
        float v[8];
        #pragma unroll
        for (int j = 0; j < 8; ++j) v[j] = base[(size_t)(g * 8 + j) * GG];
        #pragma unroll
        for (int j = 0; j < 8; ++j) {
            base[(size_t)(g * 8 + j) * GG] = run;
            run = fmaxf(run, v[j]);
        }
    }
}

// ---------------------------------------------------------------------------
// K3: per-chunk in-place running max seeded by the exclusive prefix.
// Loads explicitly staged in groups of 8 before the store chain; nontemporal
// both ways (stream-once data, keep L2 clean).
// ---------------------------------------------------------------------------
__global__ __launch_bounds__(256) void finalize_kernel(float* __restrict__ out,
                                                       const float* __restrict__ exPrefix) {
    const int c   = blockIdx.x * 2 + (threadIdx.x >> 7);
    const int col = threadIdx.x & 127;
    float run = exPrefix[(size_t)c * GG + col];
    float* p = out + (size_t)c * BM * GG + col;
    for (int g = 0; g < BM / 8; ++g) {
        float v[8];
        #pragma unroll
        for (int j = 0; j < 8; ++j)
            v[j] = __builtin_nontemporal_load(&p[(size_t)(g * 8 + j) * GG]);
        #pragma unroll
        for (int j = 0; j < 8; ++j) {
            run = fmaxf(run, v[j]);
            __builtin_nontemporal_store(run, &p[(size_t)(g * 8 + j) * GG]);
        }
    }
}

// ---------------------------------------------------------------------------
extern "C" void kernel_launch(void* const* d_in, const int* in_sizes, int n_in,
                              void* d_out, int out_size, void* d_ws, size_t ws_size,
                              hipStream_t stream) {
    const float* local = (const float*)d_in[0];   // [262144, 512]
    const float* gfeat = (const float*)d_in[1];   // [1, 128]
    const float* W1    = (const float*)d_in[2];   // [512, 128]
    const float* b1    = (const float*)d_in[3];   // [128]
    float* out = (float*)d_out;                   // [262144*128] ++ [128]

    __bf16* Bfrag   = (__bf16*)d_ws;                               // 128 KB
    float* blockMax = (float*)((char*)d_ws + (size_t)LL * GG * 2); // 1 MB

    prep_kernel<<<256, 256, 0, stream>>>(W1, Bfrag);
    gemm_kernel<<<NCHUNK, 256, 0, stream>>>(local, b1, Bfrag, out, blockMax);
    scan_kernel<<<1, 1024, 0, stream>>>(blockMax, gfeat, out + (size_t)WSZ * GG);
    finalize_kernel<<<NCHUNK / 2, 256, 0, stream>>>(out, blockMax);
}

// Round 3
// 758.475 us; speedup vs baseline: 1.1736x; 1.0705x over previous
//
#include <hip/hip_runtime.h>
#include <hip/hip_bf16.h>

// Problem constants (match reference)
#define WSZ 262144   // window size (rows)
#define LL  512      // local feature length (K)
#define GG  128      // global feature length (N)
#define BM  128      // rows per block tile
#define BK  32       // K-chunk (one MFMA K)
#define NCHUNK (WSZ / BM)   // 2048
#define NEG_INF (-__builtin_inff())

typedef float f32x4 __attribute__((ext_vector_type(4)));
typedef __bf16 bf16x8 __attribute__((ext_vector_type(8)));

#define FLAG_AGG 1u
#define FLAG_PRE 2u

static __device__ __forceinline__ unsigned long long packSV(unsigned f, float v) {
    return ((unsigned long long)f << 32) | (unsigned long long)__float_as_uint(v);
}

// ---------------------------------------------------------------------------
// K_init: zero the ticket counter and the 2048x128 lookback state array.
// Grid: 1024 x 256 = 262144 threads == state words. Runs every launch.
// ---------------------------------------------------------------------------
__global__ __launch_bounds__(256) void init_kernel(unsigned long long* __restrict__ state,
                                                   int* __restrict__ ticket) {
    int t = blockIdx.x * 256 + threadIdx.x;
    state[t] = 0ull;
    if (t == 0) *ticket = 0;
}

// ---------------------------------------------------------------------------
// K0: convert W1 (fp32 [512,128] row-major) to bf16 in MFMA-B fragment order:
//   dst[((kc*128 + col)*4 + q)*8 + j] = W1[k][col],  k = kc*32 + q*8 + j
// ---------------------------------------------------------------------------
__global__ __launch_bounds__(256) void prep_kernel(const float* __restrict__ W1,
                                                   __bf16* __restrict__ Bfrag) {
    int t = blockIdx.x * 256 + threadIdx.x;   // 0 .. 65535
    int k = t >> 7;
    int col = t & 127;
    float v = W1[t];
    int dst = ((k >> 5) << 12) + (col << 5) + (((k >> 3) & 3) << 3) + (k & 7);
    Bfrag[dst] = (__bf16)v;
}

// ---------------------------------------------------------------------------
// K1: fused GEMM + seeded cummax (decoupled lookback).
// 256 threads (2x2 waves), tile 128 rows x 128 cols. Ticket-ordered chunks.
// After MFMA: bias add, in-register intra-block column cummax, publish block
// aggregate, lookback for exclusive prefix, apply, store. One pass over A/out.
// ---------------------------------------------------------------------------
__global__ __launch_bounds__(256) void fused_kernel(
        const float* __restrict__ A,       // [WSZ, 512]
        const float* __restrict__ b1,      // [128]
        const float* __restrict__ gfeat,   // [128]
        const __bf16* __restrict__ Bfrag,  // frag-ordered W1 bf16
        unsigned long long* __restrict__ state, // [NCHUNK, 128]
        int* __restrict__ ticket,
        float* __restrict__ out,           // [WSZ, 128]
        float* __restrict__ gnew)          // [128]
{
    __shared__ __align__(16) __bf16 ldsA[BM * 40];
    __shared__ float totL[GG], totH[GG];    // per-col max of rows 0-63 / 64-127
    __shared__ float exclP0[GG], exclP1[GG];
    __shared__ int s_tk;

    const int tid  = threadIdx.x;
    if (tid == 0) s_tk = atomicAdd(ticket, 1);
    const int wave = tid >> 6;
    const int lane = tid & 63;
    const int wr = wave >> 1;
    const int wc = wave & 1;
    const int l15 = lane & 15;
    const int q   = lane >> 4;
    __syncthreads();
    const int c = s_tk;                     // chunk index (ticket-ordered)
    const size_t row0 = (size_t)c * BM;

    // staging task geometry: 512 tasks of 8 floats; this thread owns 2 tasks
    const int rowA0 = tid >> 2,         kgA0 = tid & 3;
    const int rowA1 = (tid + 256) >> 2, kgA1 = tid & 3;
    const float* sA0 = A + (row0 + rowA0) * LL + kgA0 * 8;
    const float* sA1 = A + (row0 + rowA1) * LL + kgA1 * 8;

    f32x4 acc[4][4] = {};

    f32x4 c00 = __builtin_nontemporal_load((const f32x4*)sA0);
    f32x4 c01 = __builtin_nontemporal_load((const f32x4*)(sA0 + 4));
    f32x4 c10 = __builtin_nontemporal_load((const f32x4*)sA1);
    f32x4 c11 = __builtin_nontemporal_load((const f32x4*)(sA1 + 4));

    for (int kc = 0; kc < LL / BK; ++kc) {
        bf16x8 pb0, pb1;
        pb0[0] = (__bf16)c00[0]; pb0[1] = (__bf16)c00[1];
        pb0[2] = (__bf16)c00[2]; pb0[3] = (__bf16)c00[3];
        pb0[4] = (__bf16)c01[0]; pb0[5] = (__bf16)c01[1];
        pb0[6] = (__bf16)c01[2]; pb0[7] = (__bf16)c01[3];
        pb1[0] = (__bf16)c10[0]; pb1[1] = (__bf16)c10[1];
        pb1[2] = (__bf16)c10[2]; pb1[3] = (__bf16)c10[3];
        pb1[4] = (__bf16)c11[0]; pb1[5] = (__bf16)c11[1];
        pb1[6] = (__bf16)c11[2]; pb1[7] = (__bf16)c11[3];

        __syncthreads();
        *(bf16x8*)&ldsA[rowA0 * 40 + kgA0 * 8] = pb0;
        *(bf16x8*)&ldsA[rowA1 * 40 + kgA1 * 8] = pb1;

        const int kn = (kc < LL / BK - 1) ? kc + 1 : kc;
        c00 = __builtin_nontemporal_load((const f32x4*)(sA0 + kn * BK));
        c01 = __builtin_nontemporal_load((const f32x4*)(sA0 + kn * BK + 4));
        c10 = __builtin_nontemporal_load((const f32x4*)(sA1 + kn * BK));
        c11 = __builtin_nontemporal_load((const f32x4*)(sA1 + kn * BK + 4));

        __syncthreads();

        bf16x8 bfr[4];
        #pragma unroll
        for (int ct = 0; ct < 4; ++ct) {
            int col = wc * 64 + ct * 16 + l15;
            bfr[ct] = *(const bf16x8*)(Bfrag + ((size_t)kc * 128 + col) * 32 + q * 8);
        }
        bf16x8 afr[4];
        #pragma unroll
        for (int rt = 0; rt < 4; ++rt) {
            int row = wr * 64 + rt * 16 + l15;
            afr[rt] = *(const bf16x8*)&ldsA[row * 40 + q * 8];
        }
        #pragma unroll
        for (int rt = 0; rt < 4; ++rt)
            #pragma unroll
            for (int ct = 0; ct < 4; ++ct)
                acc[rt][ct] = __builtin_amdgcn_mfma_f32_16x16x32_bf16(
                    afr[rt], bfr[ct], acc[rt][ct], 0, 0, 0);
    }

    // ================= epilogue: bias + in-register column cummax ==========
    // D-tile layout: row = q*4 + reg, col = l15.
    float carry[4];
    #pragma unroll
    for (int ct = 0; ct < 4; ++ct) {
        const int col = wc * 64 + ct * 16 + l15;
        const float bias = b1[col];
        float cy = NEG_INF;
        #pragma unroll
        for (int rt = 0; rt < 4; ++rt) {
            f32x4 v = acc[rt][ct];
            v[0] += bias; v[1] += bias; v[2] += bias; v[3] += bias;
            // in-lane prefix over the 4 regs (rows q*4 .. q*4+3)
            v[1] = fmaxf(v[1], v[0]);
            v[2] = fmaxf(v[2], v[1]);
            v[3] = fmaxf(v[3], v[2]);
            float t = v[3];                       // quad-group total
            // inclusive Hillis-Steele scan across quads (lanes q*16+l15)
            float s = __shfl_up(t, 16); t = (q >= 1) ? fmaxf(t, s) : t;
            s       = __shfl_up(t, 32); t = (q >= 2) ? fmaxf(t, s) : t;
            float e = __shfl_up(t, 16); e = (q >= 1) ? e : NEG_INF;   // excl over quads
            float tt = __shfl(t, 48 + l15);       // tile total (incl at q=3)
            float base = fmaxf(e, cy);
            v[0] = fmaxf(v[0], base); v[1] = fmaxf(v[1], base);
            v[2] = fmaxf(v[2], base); v[3] = fmaxf(v[3], base);
            acc[rt][ct] = v;
            cy = fmaxf(cy, tt);                   // carry across rt tiles
        }
        carry[ct] = cy;   // per-col max over this wave's 64 rows (q-uniform)
    }
    if (q == 0) {
        #pragma unroll
        for (int ct = 0; ct < 4; ++ct) {
            int col = wc * 64 + ct * 16 + l15;
            (wr ? totH : totL)[col] = carry[ct];
        }
    }
    __syncthreads();

    // ============ publish aggregate, lookback, publish prefix ==============
    if (tid < GG) {
        const float aL = totL[tid], aH = totH[tid];
        const float agg = fmaxf(aL, aH);
        unsigned long long* st = state + (size_t)c * GG + tid;
        float ex;
        if (c == 0) {
            ex = gfeat[tid];
        } else {
            __hip_atomic_store(st, packSV(FLAG_AGG, agg),
                               __ATOMIC_RELAXED, __HIP_MEMORY_SCOPE_AGENT);
            ex = NEG_INF;
            for (int p = c - 1; p >= 0; --p) {
                unsigned long long s = __hip_atomic_load(state + (size_t)p * GG + tid,
                                       __ATOMIC_RELAXED, __HIP_MEMORY_SCOPE_AGENT);
                while ((unsigned)(s >> 32) == 0u) {
                    __builtin_amdgcn_s_sleep(1);
                    s = __hip_atomic_load(state + (size_t)p * GG + tid,
                                          __ATOMIC_RELAXED, __HIP_MEMORY_SCOPE_AGENT);
                }
                ex = fmaxf(ex, __uint_as_float((unsigned)s));
                if ((unsigned)(s >> 32) == FLAG_PRE) break;
            }
        }
        const float inc = fmaxf(ex, agg);
        __hip_atomic_store(st, packSV(FLAG_PRE, inc),
                           __ATOMIC_RELAXED, __HIP_MEMORY_SCOPE_AGENT);
        exclP0[tid] = ex;                 // seed for rows 0-63
        exclP1[tid] = fmaxf(ex, aL);      // seed for rows 64-127
        if (c == NCHUNK - 1) gnew[tid] = inc;
    }
    __syncthreads();

    // ===================== apply seed + store ==============================
    #pragma unroll
    for (int ct = 0; ct < 4; ++ct) {
        const int col = wc * 64 + ct * 16 + l15;
        const float base = wr ? exclP1[col] : exclP0[col];
        #pragma unroll
        for (int rt = 0; rt < 4; ++rt) {
            #pragma unroll
            for (int r = 0; r < 4; ++r) {
                float v = fmaxf(acc[rt][ct][r], base);
                size_t row = row0 + wr * 64 + rt * 16 + q * 4 + r;
                __builtin_nontemporal_store(v, &out[row * GG + col]);
            }
        }
    }
}

// ---------------------------------------------------------------------------
extern "C" void kernel_launch(void* const* d_in, const int* in_sizes, int n_in,
                              void* d_out, int out_size, void* d_ws, size_t ws_size,
                              hipStream_t stream) {
    const float* local = (const float*)d_in[0];   // [262144, 512]
    const float* gfeat = (const float*)d_in[1];   // [1, 128]
    const float* W1    = (const float*)d_in[2];   // [512, 128]
    const float* b1    = (const float*)d_in[3];   // [128]
    float* out = (float*)d_out;                   // [262144*128] ++ [128]

    // ws layout: [0,128KB) Bfrag bf16; [128KB, 128KB+2MB) state; then ticket
    __bf16* Bfrag = (__bf16*)d_ws;
    unsigned long long* state = (unsigned long long*)((char*)d_ws + (size_t)LL * GG * 2);
    int* ticket = (int*)((char*)d_ws + (size_t)LL * GG * 2 + (size_t)NCHUNK * GG * 8);

    init_kernel<<<NCHUNK * GG / 256, 256, 0, stream>>>(state, ticket);
    prep_kernel<<<256, 256, 0, stream>>>(W1, Bfrag);
    fused_kernel<<<NCHUNK, 256, 0, stream>>>(local, b1, gfeat, Bfrag, state, ticket,
                                             out, out + (size_t)WSZ * GG);
}